// Round 10
// baseline (694.856 us; speedup 1.0000x reference)
//
#include <hip/hip_runtime.h>
#include <hip/hip_bf16.h>

// ---------------------------------------------------------------------------
// GIN on MI355X. Conv GEMMs: 128x128/BK=32 ring-3 depth-2 + T2 swizzle.
// Head GEMM: m201-style 2-phase-per-K-tile schedule, BK=64, dbuf, 1 WG/CU,
// per-phase {ds_read + gload issue -> barrier -> lgkmcnt(0) -> 16 MFMA ->
// barrier} so reads overlap MFMA across waves (fixes R8/R9 convoy null).
// ---------------------------------------------------------------------------

#define GIN_N_FEAT_IN 128
#define GIN_H 256
#define M_PAD_ROWS 50176   // 50000 padded to 256 (head tile height)

typedef short short8 __attribute__((ext_vector_type(8)));
typedef float f32x4 __attribute__((ext_vector_type(4)));

#define SCHED_FENCE() __builtin_amdgcn_sched_barrier(0)
#define RAW_BARRIER() __builtin_amdgcn_s_barrier()

__device__ inline ushort f32_to_bf16(float f) {
    union { float f; uint u; } x; x.f = f;
    uint r = x.u + 0x7fff + ((x.u >> 16) & 1);
    return (ushort)(r >> 16);
}
__device__ inline float bf16_to_f32(uint h) {
    union { uint u; float f; } x; x.u = h << 16;
    return x.f;
}
__device__ inline uint pack_bf16(float lo, float hi) {
    return (uint)f32_to_bf16(lo) | ((uint)f32_to_bf16(hi) << 16);
}

__device__ inline void gload_lds16(const ushort* g, ushort* l) {
    __builtin_amdgcn_global_load_lds(
        (const __attribute__((address_space(1))) void*)g,
        (__attribute__((address_space(3))) void*)l, 16, 0, 0);
}

// ---------------- conversions ----------------

__global__ void cvt_f32_bf16(const float* __restrict__ in, ushort* __restrict__ out, int npairs) {
    for (int i = blockIdx.x * blockDim.x + threadIdx.x; i < npairs; i += gridDim.x * blockDim.x) {
        float2 v = ((const float2*)in)[i];
        ((uint*)out)[i] = pack_bf16(v.x, v.y);
    }
}

// all weight transposes in one dispatch: dst[c][r] = bf16(src[r][c])
struct WPrep {
    const float* src[7];
    ushort* dst[7];
    int R[7];
    int C[7];
};

__global__ void prep_weights(WPrep p) {
    int which = blockIdx.y;
    int R = p.R[which], C = p.C[which];
    int total = R * C;
    const float* src = p.src[which];
    ushort* dst = p.dst[which];
    for (int idx = blockIdx.x * blockDim.x + threadIdx.x; idx < total;
         idx += gridDim.x * blockDim.x) {
        int r = idx / C, c = idx - r * C;
        dst[(size_t)c * R + r] = f32_to_bf16(src[idx]);
    }
}

// ---------------- CSR build ----------------

__global__ void count_kernel(const int* __restrict__ ei, int* __restrict__ deg, int E) {
    for (int e = blockIdx.x * blockDim.x + threadIdx.x; e < E; e += gridDim.x * blockDim.x) {
        atomicAdd(&deg[ei[E + e]], 1);   // dst = ei[1][e]
    }
}

__global__ void scan_chunk(const int* __restrict__ deg, int* __restrict__ row_start,
                           int* __restrict__ chunk_sums, int N) {
    __shared__ int sm[256];
    int tid = threadIdx.x;
    int idx = blockIdx.x * 256 + tid;
    int v = (idx < N) ? deg[idx] : 0;
    sm[tid] = v;
    __syncthreads();
    #pragma unroll
    for (int off = 1; off < 256; off <<= 1) {
        int t = (tid >= off) ? sm[tid - off] : 0;
        __syncthreads();
        sm[tid] += t;
        __syncthreads();
    }
    if (idx < N) row_start[idx] = sm[tid] - v;
    if (tid == 255) chunk_sums[blockIdx.x] = sm[255];
}

__global__ void scan_tops(int* __restrict__ chunk_sums, int* __restrict__ row_start,
                          int nchunks, int N, int E) {
    __shared__ int sm[256];
    int tid = threadIdx.x;
    int v = (tid < nchunks) ? chunk_sums[tid] : 0;
    sm[tid] = v;
    __syncthreads();
    #pragma unroll
    for (int off = 1; off < 256; off <<= 1) {
        int t = (tid >= off) ? sm[tid - off] : 0;
        __syncthreads();
        sm[tid] += t;
        __syncthreads();
    }
    if (tid < nchunks) chunk_sums[tid] = sm[tid] - v;
    if (tid == 0) row_start[N] = E;
}

__global__ void scan_add(int* __restrict__ row_start, int* __restrict__ cursor,
                         const int* __restrict__ chunk_sums, int N) {
    int idx = blockIdx.x * 256 + threadIdx.x;
    if (idx < N) {
        int v = row_start[idx] + chunk_sums[blockIdx.x];
        row_start[idx] = v;
        cursor[idx] = v;
    }
}

__global__ void scatter_kernel(const int* __restrict__ ei, int* __restrict__ cursor,
                               int* __restrict__ perm, int E) {
    for (int e = blockIdx.x * blockDim.x + threadIdx.x; e < E; e += gridDim.x * blockDim.x) {
        int d = ei[E + e];
        int pos = atomicAdd(&cursor[d], 1);
        perm[pos] = ei[e];
    }
}

// ---------------- aggregation ----------------
// W=128 (layer 0): wave-per-node, unroll-4 ILP.

__global__ void agg128(const ushort* __restrict__ xsrc,
                       const int* __restrict__ row_start, const int* __restrict__ perm,
                       ushort* __restrict__ out, int N) {
    int node = blockIdx.x * 4 + (threadIdx.x >> 6);
    if (node >= N) return;
    const int lane = threadIdx.x & 63;
    const size_t loff = (size_t)lane * 2;
    const ushort* base = xsrc + loff;

    float lo, hi;
    {
        uint v = *(const uint*)(base + (size_t)node * 128);
        lo = bf16_to_f32(v & 0xffffu); hi = bf16_to_f32(v >> 16);
    }
    const int s = row_start[node], e = row_start[node + 1];
    int j = s;
    for (; j + 4 <= e; j += 4) {
        int n0 = perm[j], n1 = perm[j + 1], n2 = perm[j + 2], n3 = perm[j + 3];
        uint w0 = *(const uint*)(base + (size_t)n0 * 128);
        uint w1 = *(const uint*)(base + (size_t)n1 * 128);
        uint w2 = *(const uint*)(base + (size_t)n2 * 128);
        uint w3 = *(const uint*)(base + (size_t)n3 * 128);
        lo += bf16_to_f32(w0 & 0xffffu) + bf16_to_f32(w1 & 0xffffu)
            + bf16_to_f32(w2 & 0xffffu) + bf16_to_f32(w3 & 0xffffu);
        hi += bf16_to_f32(w0 >> 16) + bf16_to_f32(w1 >> 16)
            + bf16_to_f32(w2 >> 16) + bf16_to_f32(w3 >> 16);
    }
    for (; j < e; ++j) {
        uint w = *(const uint*)(base + (size_t)perm[j] * 128);
        lo += bf16_to_f32(w & 0xffffu);
        hi += bf16_to_f32(w >> 16);
    }
    *(uint*)(out + (size_t)node * 128 + loff) = pack_bf16(lo, hi);
}

// W=256 (layers 1,2): TWO waves per node (128 cols each) for 2x memory-level
// parallelism against L3 latency. Per-column sum order unchanged.

__global__ void agg256_split(const ushort* __restrict__ xsrc, int stride,
                             const int* __restrict__ row_start, const int* __restrict__ perm,
                             ushort* __restrict__ out, int N) {
    const int wid = threadIdx.x >> 6;
    const int node = blockIdx.x * 2 + (wid >> 1);
    if (node >= N) return;
    const int lane = threadIdx.x & 63;
    const int col = (wid & 1) * 128 + lane * 2;
    const ushort* base = xsrc + col;

    float lo, hi;
    {
        uint v = *(const uint*)(base + (size_t)node * stride);
        lo = bf16_to_f32(v & 0xffffu); hi = bf16_to_f32(v >> 16);
    }
    const int s = row_start[node], e = row_start[node + 1];
    int j = s;
    for (; j + 4 <= e; j += 4) {
        int n0 = perm[j], n1 = perm[j + 1], n2 = perm[j + 2], n3 = perm[j + 3];
        uint w0 = *(const uint*)(base + (size_t)n0 * stride);
        uint w1 = *(const uint*)(base + (size_t)n1 * stride);
        uint w2 = *(const uint*)(base + (size_t)n2 * stride);
        uint w3 = *(const uint*)(base + (size_t)n3 * stride);
        lo += bf16_to_f32(w0 & 0xffffu) + bf16_to_f32(w1 & 0xffffu)
            + bf16_to_f32(w2 & 0xffffu) + bf16_to_f32(w3 & 0xffffu);
        hi += bf16_to_f32(w0 >> 16) + bf16_to_f32(w1 >> 16)
            + bf16_to_f32(w2 >> 16) + bf16_to_f32(w3 >> 16);
    }
    for (; j < e; ++j) {
        uint w = *(const uint*)(base + (size_t)perm[j] * stride);
        lo += bf16_to_f32(w & 0xffffu);
        hi += bf16_to_f32(w >> 16);
    }
    *(uint*)(out + (size_t)node * 256 + col) = pack_bf16(lo, hi);
}

// ---------------- conv bf16 MFMA GEMM: 128x128, BK=32, ring-3 depth-2 --------
// (unchanged from R9; not in top-5)

template <int MODE>
__global__ __launch_bounds__(256) void gemm_mfma(
    const ushort* __restrict__ A, const ushort* __restrict__ Bt,
    const float* __restrict__ bias, void* __restrict__ Cout,
    int ldc, int K, float* __restrict__ extra, int Nvalid) {
    __shared__ ushort As[3][128 * 32];
    __shared__ ushort Bs[3][128 * 32];
    const int tid = threadIdx.x;

    const int gx = gridDim.x;
    const int nwg = gx * gridDim.y;
    const int flat = blockIdx.y * gx + blockIdx.x;
    const int q = nwg >> 3, r = nwg & 7;
    const int xcd = flat & 7, loc = flat >> 3;
    const int wg = (xcd < r ? xcd * (q + 1) : r * (q + 1) + (xcd - r) * q) + loc;
    const int bm = (wg / gx) * 128;
    const int bn = (wg % gx) * 128;

    const int lane = tid & 63;
    const int wid = tid >> 6;
    const int wr = wid >> 1, wc = wid & 1;

    f32x4 acc[4][4] = {};

    const int arow = tid >> 2;
    const int gcol = ((tid & 3) ^ ((tid >> 3) & 3)) * 8;
    const ushort* Ag0 = A + (size_t)(bm + arow) * K + gcol;
    const ushort* Ag1 = A + (size_t)(bm + 64 + arow) * K + gcol;
    const ushort* Bg0 = Bt + (size_t)(bn + arow) * K + gcol;
    const ushort* Bg1 = Bt + (size_t)(bn + 64 + arow) * K + gcol;
    const int wofs = (tid & ~63) * 8;

    const int fr = lane & 15;
    const int rchunk = ((lane >> 4) ^ ((fr >> 1) & 3)) * 8;

    const int NT = K >> 5;

    #pragma unroll
    for (int t = 0; t < 2; ++t) {
        const int k0 = t << 5;
        ushort* a = As[t]; ushort* b = Bs[t];
        gload_lds16(Ag0 + k0, a + wofs);
        gload_lds16(Ag1 + k0, a + 2048 + wofs);
        gload_lds16(Bg0 + k0, b + wofs);
        gload_lds16(Bg1 + k0, b + 2048 + wofs);
    }

    int sl = 0;
    for (int it = 0; it < NT; ++it) {
        if (it + 2 < NT) {
            int wsl = sl + 2; if (wsl >= 3) wsl -= 3;
            const int k0 = (it + 2) << 5;
            ushort* a = As[wsl]; ushort* b = Bs[wsl];
            gload_lds16(Ag0 + k0, a + wofs);
            gload_lds16(Ag1 + k0, a + 2048 + wofs);
            gload_lds16(Bg0 + k0, b + wofs);
            gload_lds16(Bg1 + k0, b + 2048 + wofs);
            asm volatile("s_waitcnt vmcnt(8)" ::: "memory");
        } else if (it + 1 < NT) {
            asm volatile("s_waitcnt vmcnt(4)" ::: "memory");
        } else {
            asm volatile("s_waitcnt vmcnt(0)" ::: "memory");
        }
        SCHED_FENCE();
        RAW_BARRIER();

        const ushort* as = As[sl];
        const ushort* bs = Bs[sl];
        short8 af[4], bf[4];
        #pragma unroll
        for (int m = 0; m < 4; ++m)
            af[m] = *(const short8*)&as[(wr * 64 + m * 16 + fr) * 32 + rchunk];
        #pragma unroll
        for (int n = 0; n < 4; ++n)
            bf[n] = *(const short8*)&bs[(wc * 64 + n * 16 + fr) * 32 + rchunk];
        __builtin_amdgcn_s_setprio(1);
        #pragma unroll
        for (int m = 0; m < 4; ++m)
            #pragma unroll
            for (int n = 0; n < 4; ++n)
                acc[m][n] = __builtin_amdgcn_mfma_f32_16x16x32_bf16(af[m], bf[n], acc[m][n], 0, 0, 0);
        __builtin_amdgcn_s_setprio(0);

        asm volatile("s_waitcnt lgkmcnt(0)" ::: "memory");
        SCHED_FENCE();
        RAW_BARRIER();
        sl = sl + 1; if (sl >= 3) sl -= 3;
    }

    float s1[4], s2[4];
    if constexpr (MODE == 0) {
        #pragma unroll
        for (int n = 0; n < 4; ++n) { s1[n] = 0.f; s2[n] = 0.f; }
    }
    #pragma unroll
    for (int n = 0; n < 4; ++n) {
        const int col = bn + wc * 64 + n * 16 + fr;
        const float bv = bias[col];
        #pragma unroll
        for (int m = 0; m < 4; ++m) {
            const int row0 = bm + wr * 64 + m * 16 + (lane >> 4) * 4;
            #pragma unroll
            for (int rr = 0; rr < 4; ++rr) {
                float v = acc[m][n][rr] + bv;
                if constexpr (MODE == 1) {
                    v = fmaxf(v, 0.f);
                    ((ushort*)Cout)[(size_t)(row0 + rr) * ldc + col] = f32_to_bf16(v);
                } else {
                    ((float*)Cout)[(size_t)(row0 + rr) * ldc + col] = v;
                    if (row0 + rr < Nvalid) { s1[n] += v; s2[n] += v * v; }
                }
            }
        }
    }
    if constexpr (MODE == 0) {
        #pragma unroll
        for (int n = 0; n < 4; ++n) {
            float a = s1[n], b = s2[n];
            a += __shfl_xor(a, 16); b += __shfl_xor(b, 16);
            a += __shfl_xor(a, 32); b += __shfl_xor(b, 32);
            if ((lane >> 4) == 0) {
                int col = bn + wc * 64 + n * 16 + fr;
                atomicAdd(&extra[col], a);
                atomicAdd(&extra[256 + col], b);
            }
        }
    }
}

// ---------------- head GEMM: 256x128, BK=64, 8 waves, 2-phase/K-tile ---------
// m201-style: per phase {ds_read frags + issue gloads -> barrier -> lgkmcnt(0)
// -> setprio(1) 16 MFMA setprio(0) -> barrier}. Dbuf LDS, 1 WG/CU.
// LDS rows are 128 B = 8 chunks; stored chunk = c ^ (row&7) -> 2-way free.

__global__ __launch_bounds__(512) void gemm_head(
    const ushort* __restrict__ A,    // Hcat [MP x 768]
    const ushort* __restrict__ Bt,   // lin1t [768 x 768]
    const float* __restrict__ bias,  // lin1_b [768]
    const float* __restrict__ w2,    // lin2_W [768 x 2]
    float* __restrict__ part,        // [6][MP][2]
    int K, int MP) {
    __shared__ ushort As[2][256 * 64];  // 64 KB
    __shared__ ushort Bs[2][128 * 64];  // 32 KB
    __shared__ float sm_part[256][2];   // 2 KB  -> 98 KB, 1 WG/CU
    const int tid = threadIdx.x;

    // XCD-bijective swizzle (nwg = 6*196 = 1176, %8==0)
    const int gx = gridDim.x;
    const int nwg = gx * gridDim.y;
    const int flat = blockIdx.y * gx + blockIdx.x;
    const int q = nwg >> 3, r = nwg & 7;
    const int xcd = flat & 7, loc = flat >> 3;
    const int wg = (xcd < r ? xcd * (q + 1) : r * (q + 1) + (xcd - r) * q) + loc;
    const int bm = (wg / gx) * 256;
    const int bn = (wg % gx) * 128;
    const int coltile = wg % gx;

    const int lane = tid & 63;
    const int wid = tid >> 6;        // 0..7
    const int wr = wid >> 1;         // 0..3 (64-row band of 256)
    const int wc = wid & 1;          // 0..1 (64-col half of 128)

    sm_part[tid >> 1][tid & 1] = 0.f;

    f32x4 acc[4][4] = {};

    // staging: thread t -> row t>>3 (64 rows/pass), stored chunk t&7;
    // global chunk = (t&7) ^ ((t>>3)&7)  [inverse of stored swizzle]
    const int srow = tid >> 3;
    const int sgc = ((tid & 7) ^ ((tid >> 3) & 7)) * 8;
    const ushort* AgBase = A + (size_t)(bm + srow) * K + sgc;
    const ushort* BgBase = Bt + (size_t)(bn + srow) * K + sgc;
    const size_t rowK64 = (size_t)64 * K;
    const int wofs = (tid & ~63) * 8;   // wave-uniform; HW adds lane*16B

    const int fr = lane & 15;
    const int ch = lane >> 4;            // logical k-chunk within 32-k half

    const int NT = K >> 6;   // 12

    // prologue: stage tile 0 (6 loads: A passes 0-3, B passes 0-1)
    {
        ushort* a = As[0]; ushort* b = Bs[0];
        gload_lds16(AgBase + 0 * rowK64, a + 0 * 4096 + wofs);
        gload_lds16(AgBase + 1 * rowK64, a + 1 * 4096 + wofs);
        gload_lds16(AgBase + 2 * rowK64, a + 2 * 4096 + wofs);
        gload_lds16(AgBase + 3 * rowK64, a + 3 * 4096 + wofs);
        gload_lds16(BgBase + 0 * rowK64, b + 0 * 4096 + wofs);
        gload_lds16(BgBase + 1 * rowK64, b + 1 * 4096 + wofs);
    }

    for (int it = 0; it < NT; ++it) {
        // tile-top: current buf resident (its 6 loads are all outstanding ones)
        asm volatile("s_waitcnt vmcnt(0)" ::: "memory");
        SCHED_FENCE();
        RAW_BARRIER();

        const ushort* as = As[it & 1];
        const ushort* bs = Bs[it & 1];
        ushort* an = As[(it + 1) & 1];
        ushort* bnx = Bs[(it + 1) & 1];
        const bool pf = (it + 1 < NT);
        const int kg = (it + 1) << 6;

        short8 bfr[4][2], afr[2][2];

        // ---- phase 0: read af[0..1]+bf[all]; gload A0,A1,A2; MFMA m=0,1 ----
        #pragma unroll
        for (int n = 0; n < 4; ++n) {
            const int row = wc * 64 + n * 16 + fr;
            #pragma unroll
            for (int ks = 0; ks < 2; ++ks) {
                const int c = ks * 4 + ch;
                bfr[n][ks] = *(const short8*)&bs[row * 64 + ((c ^ (row & 7)) * 8)];
            }
        }
        #pragma unroll
        for (int m = 0; m < 2; ++m) {
            const int row = wr * 64 + m * 16 + fr;
            #pragma unroll
            for (int ks = 0; ks < 2; ++ks) {
                const int c = ks * 4 + ch;
                afr[m][ks] = *(const short8*)&as[row * 64 + ((c ^ (row & 7)) * 8)];
            }
        }
        if (pf) {
            gload_lds16(AgBase + kg + 0 * rowK64, an + 0 * 4096 + wofs);
            gload_lds16(AgBase + kg + 1 * rowK64, an + 1 * 4096 + wofs);
            gload_lds16(AgBase + kg + 2 * rowK64, an + 2 * 4096 + wofs);
        }
        RAW_BARRIER();
        asm volatile("s_waitcnt lgkmcnt(0)" ::: "memory");
        SCHED_FENCE();
        __builtin_amdgcn_s_setprio(1);
        #pragma unroll
        for (int m = 0; m < 2; ++m)
            #pragma unroll
            for (int ks = 0; ks < 2; ++ks)
                #pragma unroll
                for (int n = 0; n < 4; ++n)
                    acc[m][n] = __builtin_amdgcn_mfma_f32_16x16x32_bf16(
                        afr[m][ks], bfr[n][ks], acc[m][n], 0, 0, 0);
        __builtin_amdgcn_s_setprio(0);
        SCHED_FENCE();
        RAW_BARRIER();

        // ---- phase 1: read af[2..3]; gload A3,B0,B1; MFMA m=2,3 ----
        #pragma unroll
        for (int m = 0; m < 2; ++m) {
            const int row = wr * 64 + (m + 2) * 16 + fr;
            #pragma unroll
            for (int ks = 0; ks < 2; ++ks) {
                const int c = ks * 4 + ch;
                afr[m][ks] = *(const short8*)&as[row * 64 + ((c ^ (row & 7)) * 8)];
            }
        }
        if (pf) {
            gload_lds16(AgBase + kg + 3 * rowK64, an + 3 * 4096 + wofs);
            gload_lds16(BgBase + kg + 0 * rowK64, bnx + 0 * 4096 + wofs);
            gload_lds16(BgBase + kg + 1 * rowK64, bnx + 1 * 4096 + wofs);
        }
        RAW_BARRIER();
        asm volatile("s_waitcnt lgkmcnt(0)" ::: "memory");
        SCHED_FENCE();
        __builtin_amdgcn_s_setprio(1);
        #pragma unroll
        for (int m = 0; m < 2; ++m)
            #pragma unroll
            for (int ks = 0; ks < 2; ++ks)
                #pragma unroll
                for (int n = 0; n < 4; ++n)
                    acc[m + 2][n] = __builtin_amdgcn_mfma_f32_16x16x32_bf16(
                        afr[m][ks], bfr[n][ks], acc[m + 2][n], 0, 0, 0);
        __builtin_amdgcn_s_setprio(0);
        // no trailing barrier: next tile-top {vmcnt(0); barrier} covers reuse
    }

    // epilogue: relu(v+bias) dot w2 -> reduce over fr -> LDS combine
    #pragma unroll
    for (int m = 0; m < 4; ++m) {
        #pragma unroll
        for (int rr = 0; rr < 4; ++rr) {
            float o0 = 0.f, o1 = 0.f;
            #pragma unroll
            for (int n = 0; n < 4; ++n) {
                int col = bn + wc * 64 + n * 16 + fr;
                float v = fmaxf(acc[m][n][rr] + bias[col], 0.f);
                o0 = fmaf(v, w2[col * 2 + 0], o0);
                o1 = fmaf(v, w2[col * 2 + 1], o1);
            }
            o0 += __shfl_xor(o0, 1); o1 += __shfl_xor(o1, 1);
            o0 += __shfl_xor(o0, 2); o1 += __shfl_xor(o1, 2);
            o0 += __shfl_xor(o0, 4); o1 += __shfl_xor(o1, 4);
            o0 += __shfl_xor(o0, 8); o1 += __shfl_xor(o1, 8);
            if (fr == 0) {
                int lrow = wr * 64 + m * 16 + (lane >> 4) * 4 + rr;
                atomicAdd(&sm_part[lrow][0], o0);
                atomicAdd(&sm_part[lrow][1], o1);
            }
        }
    }
    __syncthreads();
    {
        int lrow = tid >> 1, comp = tid & 1;
        part[((size_t)coltile * MP + bm + lrow) * 2 + comp] = sm_part[lrow][comp];
    }
}

// ---------------- BN apply (normalize + relu, write bf16) ----------------

__global__ void bn_apply(const float* __restrict__ h, const float* __restrict__ sums,
                         const float* __restrict__ g, const float* __restrict__ be,
                         ushort* __restrict__ outb, int Nrows) {
    int total = Nrows * 128;
    float inv = 1.0f / (float)Nrows;
    for (int idx = blockIdx.x * blockDim.x + threadIdx.x; idx < total;
         idx += gridDim.x * blockDim.x) {
        int row = idx >> 7;
        int cp = (idx & 127) * 2;
        float2 v = *(const float2*)(h + (size_t)row * 256 + cp);
        float mu0 = sums[cp] * inv,     mu1 = sums[cp + 1] * inv;
        float va0 = sums[256 + cp] * inv - mu0 * mu0;
        float va1 = sums[257 + cp] * inv - mu1 * mu1;
        float o0 = fmaxf((v.x - mu0) * rsqrtf(va0 + 1e-5f) * g[cp]     + be[cp],     0.f);
        float o1 = fmaxf((v.y - mu1) * rsqrtf(va1 + 1e-5f) * g[cp + 1] + be[cp + 1], 0.f);
        *(uint*)(outb + (size_t)row * 256 + cp) = pack_bf16(o0, o1);
    }
}

// ---------------- finalize: sum 6 partials + bias + softmax ----------------

__global__ void finalize6(const float* __restrict__ part, const float* __restrict__ b2,
                          float* __restrict__ out, int Nrows, int MP) {
    int i = blockIdx.x * blockDim.x + threadIdx.x;
    if (i >= Nrows) return;
    float h0 = b2[0], h1 = b2[1];
    #pragma unroll
    for (int c = 0; c < 6; ++c) {
        h0 += part[((size_t)c * MP + i) * 2 + 0];
        h1 += part[((size_t)c * MP + i) * 2 + 1];
    }
    out[2 * i] = h0;
    out[2 * i + 1] = h1;
    float m = fmaxf(h0, h1);
    float e0 = expf(h0 - m), e1 = expf(h1 - m);
    float s = e0 + e1;
    out[(size_t)2 * Nrows + 2 * i] = e0 / s;
    out[(size_t)2 * Nrows + 2 * i + 1] = e1 / s;
}

// ---------------------------------------------------------------------------

extern "C" void kernel_launch(void* const* d_in, const int* in_sizes, int n_in,
                              void* d_out, int out_size, void* d_ws, size_t ws_size,
                              hipStream_t stream) {
    const int N = in_sizes[0] / GIN_N_FEAT_IN;     // 50000
    const int E = in_sizes[1] / 2;                 // 800000
    const int MP = M_PAD_ROWS;
    const int nchunks = (N + 255) / 256;           // 196

    const float* x  = (const float*)d_in[0];
    const int*   ei = (const int*)d_in[1];
    const float* cW1[3] = {(const float*)d_in[2],  (const float*)d_in[8],  (const float*)d_in[14]};
    const float* cb1[3] = {(const float*)d_in[3],  (const float*)d_in[9],  (const float*)d_in[15]};
    const float* cg [3] = {(const float*)d_in[4],  (const float*)d_in[10], (const float*)d_in[16]};
    const float* cbe[3] = {(const float*)d_in[5],  (const float*)d_in[11], (const float*)d_in[17]};
    const float* cW2[3] = {(const float*)d_in[6],  (const float*)d_in[12], (const float*)d_in[18]};
    const float* cb2[3] = {(const float*)d_in[7],  (const float*)d_in[13], (const float*)d_in[19]};
    const float* lin1_W = (const float*)d_in[20];  // [768,768]
    const float* lin1_b = (const float*)d_in[21];
    const float* lin2_W = (const float*)d_in[22];  // [768,2]
    const float* lin2_b = (const float*)d_in[23];
    float* out = (float*)d_out;

    // ---- workspace carve-up (row buffers padded to MP rows) ----
    char* ws = (char*)d_ws;
    size_t off = 0;
    auto carve = [&](size_t bytes) {
        void* p = ws + off;
        off += (bytes + 255) & ~(size_t)255;
        return p;
    };
    ushort* Hcat   = (ushort*)carve((size_t)MP * 768 * 2);   // bf16 h1|h2|h3
    float*  hlin   = (float*) carve((size_t)MP * 256 * 4);   // f32 gemm1 out
    ushort* hlin_b = (ushort*)carve((size_t)MP * 256 * 2);   // bf16 after BN
    ushort* hpre   = (ushort*)carve((size_t)MP * 256 * 2);   // bf16 agg out
    ushort* xb     = (ushort*)carve((size_t)MP * 128 * 2);   // bf16 input
    ushort* w1t[3] = {(ushort*)carve(256 * 256 * 2), (ushort*)carve(256 * 256 * 2),
                      (ushort*)carve(256 * 256 * 2)};
    ushort* w2t[3] = {(ushort*)carve(256 * 256 * 2), (ushort*)carve(256 * 256 * 2),
                      (ushort*)carve(256 * 256 * 2)};
    ushort* lin1t  = (ushort*)carve((size_t)768 * 768 * 2);
    int*   row_st  = (int*)carve((size_t)(N + 1) * 4);
    int*   cursor  = (int*)carve((size_t)N * 4);
    int*   perm    = (int*)carve((size_t)E * 4);
    int*   csums   = (int*)carve(256 * 4);
    float* bnsums  = (float*)carve(512 * 4);
    float* part    = (float*)carve((size_t)6 * MP * 2 * 4);
    (void)ws_size;

    // ---- conversions ----
    cvt_f32_bf16<<<1024, 256, 0, stream>>>(x, xb, N * 64);
    WPrep wp;
    wp.src[0] = cW1[0]; wp.dst[0] = w1t[0]; wp.R[0] = 128; wp.C[0] = 256;
    wp.src[1] = cW1[1]; wp.dst[1] = w1t[1]; wp.R[1] = 256; wp.C[1] = 256;
    wp.src[2] = cW1[2]; wp.dst[2] = w1t[2]; wp.R[2] = 256; wp.C[2] = 256;
    wp.src[3] = cW2[0]; wp.dst[3] = w2t[0]; wp.R[3] = 256; wp.C[3] = 256;
    wp.src[4] = cW2[1]; wp.dst[4] = w2t[1]; wp.R[4] = 256; wp.C[4] = 256;
    wp.src[5] = cW2[2]; wp.dst[5] = w2t[2]; wp.R[5] = 256; wp.C[5] = 256;
    wp.src[6] = lin1_W; wp.dst[6] = lin1t;  wp.R[6] = 768; wp.C[6] = 768;
    prep_weights<<<dim3(576, 7), 256, 0, stream>>>(wp);

    // ---- CSR build (3-stage parallel scan) ----
    hipMemsetAsync(cursor, 0, (size_t)N * 4, stream);
    count_kernel<<<1024, 256, 0, stream>>>(ei, cursor, E);
    scan_chunk<<<nchunks, 256, 0, stream>>>(cursor, row_st, csums, N);
    scan_tops<<<1, 256, 0, stream>>>(csums, row_st, nchunks, N, E);
    scan_add<<<nchunks, 256, 0, stream>>>(row_st, cursor, csums, N);
    scatter_kernel<<<1024, 256, 0, stream>>>(ei, cursor, perm, E);

    const dim3 ggrid(2, MP / 128);       // conv GEMMs (784 WGs, %8==0)

    // ---- 3 GIN conv layers ----
    for (int L = 0; L < 3; ++L) {
        if (L == 0)
            agg128<<<(N + 3) / 4, 256, 0, stream>>>(xb, row_st, perm, hpre, N);
        else
            agg256_split<<<(N + 1) / 2, 256, 0, stream>>>(
                Hcat + (size_t)(L - 1) * 256, 768, row_st, perm, hpre, N);

        // GEMM1 + fused BN stats
        hipMemsetAsync(bnsums, 0, 512 * 4, stream);
        gemm_mfma<0><<<ggrid, 256, 0, stream>>>(
            hpre, w1t[L], cb1[L], hlin, 256, (L == 0) ? 128 : 256, bnsums, N);

        bn_apply<<<2048, 256, 0, stream>>>(hlin, bnsums, cg[L], cbe[L], hlin_b, N);

        // GEMM2 -> Hcat column block L (bf16, ldc=768)
        gemm_mfma<1><<<ggrid, 256, 0, stream>>>(
            hlin_b, w2t[L], cb2[L], (void*)(Hcat + (size_t)L * 256), 768, 256,
            nullptr, 0);
    }

    // ---- head: 256x128-tile, BK=64, 2-phase fused gemm ----
    gemm_head<<<dim3(6, MP / 256), 512, 0, stream>>>(
        Hcat, lin1t, lin1_b, lin2_W, part, 768, MP);

    finalize6<<<(N + 255) / 256, 256, 0, stream>>>(part, lin2_b, out, N, MP);
}

// Round 11
// 683.227 us; speedup vs baseline: 1.0170x; 1.0170x over previous
//
#include <hip/hip_runtime.h>
#include <hip/hip_bf16.h>

// ---------------------------------------------------------------------------
// GIN on MI355X. Conv GEMMs: 128x128/BK=32 ring-3 depth-2 + T2 swizzle.
// Head GEMM (R11): m201 GEOMETRY — 256x256 tile, BK=64, 8 waves, per-wave
// 128x64 (8x4 frag reuse -> 384 LDS-B/MFMA vs 512 before; LDS-BW balance),
// dbuf LDS + counted vmcnt(8). Fused relu+lin2 epilogue, atomic-free global.
// ---------------------------------------------------------------------------

#define GIN_N_FEAT_IN 128
#define GIN_H 256
#define M_PAD_ROWS 50176   // 50000 padded to 256 (head tile height)

typedef short short8 __attribute__((ext_vector_type(8)));
typedef float f32x4 __attribute__((ext_vector_type(4)));

#define SCHED_FENCE() __builtin_amdgcn_sched_barrier(0)
#define RAW_BARRIER() __builtin_amdgcn_s_barrier()

__device__ inline ushort f32_to_bf16(float f) {
    union { float f; uint u; } x; x.f = f;
    uint r = x.u + 0x7fff + ((x.u >> 16) & 1);
    return (ushort)(r >> 16);
}
__device__ inline float bf16_to_f32(uint h) {
    union { uint u; float f; } x; x.u = h << 16;
    return x.f;
}
__device__ inline uint pack_bf16(float lo, float hi) {
    return (uint)f32_to_bf16(lo) | ((uint)f32_to_bf16(hi) << 16);
}

__device__ inline void gload_lds16(const ushort* g, ushort* l) {
    __builtin_amdgcn_global_load_lds(
        (const __attribute__((address_space(1))) void*)g,
        (__attribute__((address_space(3))) void*)l, 16, 0, 0);
}

// ---------------- conversions ----------------

__global__ void cvt_f32_bf16(const float* __restrict__ in, ushort* __restrict__ out, int npairs) {
    for (int i = blockIdx.x * blockDim.x + threadIdx.x; i < npairs; i += gridDim.x * blockDim.x) {
        float2 v = ((const float2*)in)[i];
        ((uint*)out)[i] = pack_bf16(v.x, v.y);
    }
}

// all weight transposes in one dispatch: dst[c][r] = bf16(src[r][c])
struct WPrep {
    const float* src[7];
    ushort* dst[7];
    int R[7];
    int C[7];
};

__global__ void prep_weights(WPrep p) {
    int which = blockIdx.y;
    int R = p.R[which], C = p.C[which];
    int total = R * C;
    const float* src = p.src[which];
    ushort* dst = p.dst[which];
    for (int idx = blockIdx.x * blockDim.x + threadIdx.x; idx < total;
         idx += gridDim.x * blockDim.x) {
        int r = idx / C, c = idx - r * C;
        dst[(size_t)c * R + r] = f32_to_bf16(src[idx]);
    }
}

// ---------------- CSR build ----------------

__global__ void count_kernel(const int* __restrict__ ei, int* __restrict__ deg, int E) {
    for (int e = blockIdx.x * blockDim.x + threadIdx.x; e < E; e += gridDim.x * blockDim.x) {
        atomicAdd(&deg[ei[E + e]], 1);   // dst = ei[1][e]
    }
}

__global__ void scan_chunk(const int* __restrict__ deg, int* __restrict__ row_start,
                           int* __restrict__ chunk_sums, int N) {
    __shared__ int sm[256];
    int tid = threadIdx.x;
    int idx = blockIdx.x * 256 + tid;
    int v = (idx < N) ? deg[idx] : 0;
    sm[tid] = v;
    __syncthreads();
    #pragma unroll
    for (int off = 1; off < 256; off <<= 1) {
        int t = (tid >= off) ? sm[tid - off] : 0;
        __syncthreads();
        sm[tid] += t;
        __syncthreads();
    }
    if (idx < N) row_start[idx] = sm[tid] - v;
    if (tid == 255) chunk_sums[blockIdx.x] = sm[255];
}

__global__ void scan_tops(int* __restrict__ chunk_sums, int* __restrict__ row_start,
                          int nchunks, int N, int E) {
    __shared__ int sm[256];
    int tid = threadIdx.x;
    int v = (tid < nchunks) ? chunk_sums[tid] : 0;
    sm[tid] = v;
    __syncthreads();
    #pragma unroll
    for (int off = 1; off < 256; off <<= 1) {
        int t = (tid >= off) ? sm[tid - off] : 0;
        __syncthreads();
        sm[tid] += t;
        __syncthreads();
    }
    if (tid < nchunks) chunk_sums[tid] = sm[tid] - v;
    if (tid == 0) row_start[N] = E;
}

__global__ void scan_add(int* __restrict__ row_start, int* __restrict__ cursor,
                         const int* __restrict__ chunk_sums, int N) {
    int idx = blockIdx.x * 256 + threadIdx.x;
    if (idx < N) {
        int v = row_start[idx] + chunk_sums[blockIdx.x];
        row_start[idx] = v;
        cursor[idx] = v;
    }
}

__global__ void scatter_kernel(const int* __restrict__ ei, int* __restrict__ cursor,
                               int* __restrict__ perm, int E) {
    for (int e = blockIdx.x * blockDim.x + threadIdx.x; e < E; e += gridDim.x * blockDim.x) {
        int d = ei[E + e];
        int pos = atomicAdd(&cursor[d], 1);
        perm[pos] = ei[e];
    }
}

// ---------------- aggregation: wave-per-node, unroll-4 ILP (R9 version) -----

template <int W>
__global__ void agg2(const ushort* __restrict__ xsrc, int stride,
                     const int* __restrict__ row_start, const int* __restrict__ perm,
                     ushort* __restrict__ out, int N) {
    constexpr int PL = W / 64;                 // bf16 per lane: 2 or 4
    int node = blockIdx.x * 4 + (threadIdx.x >> 6);
    if (node >= N) return;
    const int lane = threadIdx.x & 63;
    const size_t loff = (size_t)lane * PL;

    float af[PL];
    {
        const ushort* p = xsrc + (size_t)node * stride + loff;
        if constexpr (W == 256) {
            uint2 v = *(const uint2*)p;
            af[0] = bf16_to_f32(v.x & 0xffffu); af[1] = bf16_to_f32(v.x >> 16);
            af[2] = bf16_to_f32(v.y & 0xffffu); af[3] = bf16_to_f32(v.y >> 16);
        } else {
            uint v = *(const uint*)p;
            af[0] = bf16_to_f32(v & 0xffffu); af[1] = bf16_to_f32(v >> 16);
        }
    }
    const int s = row_start[node], e = row_start[node + 1];
    int j = s;
    for (; j + 4 <= e; j += 4) {
        int n0 = perm[j], n1 = perm[j + 1], n2 = perm[j + 2], n3 = perm[j + 3];
        if constexpr (W == 256) {
            uint2 w0 = *(const uint2*)(xsrc + (size_t)n0 * stride + loff);
            uint2 w1 = *(const uint2*)(xsrc + (size_t)n1 * stride + loff);
            uint2 w2 = *(const uint2*)(xsrc + (size_t)n2 * stride + loff);
            uint2 w3 = *(const uint2*)(xsrc + (size_t)n3 * stride + loff);
            af[0] += bf16_to_f32(w0.x & 0xffffu) + bf16_to_f32(w1.x & 0xffffu)
                   + bf16_to_f32(w2.x & 0xffffu) + bf16_to_f32(w3.x & 0xffffu);
            af[1] += bf16_to_f32(w0.x >> 16) + bf16_to_f32(w1.x >> 16)
                   + bf16_to_f32(w2.x >> 16) + bf16_to_f32(w3.x >> 16);
            af[2] += bf16_to_f32(w0.y & 0xffffu) + bf16_to_f32(w1.y & 0xffffu)
                   + bf16_to_f32(w2.y & 0xffffu) + bf16_to_f32(w3.y & 0xffffu);
            af[3] += bf16_to_f32(w0.y >> 16) + bf16_to_f32(w1.y >> 16)
                   + bf16_to_f32(w2.y >> 16) + bf16_to_f32(w3.y >> 16);
        } else {
            uint w0 = *(const uint*)(xsrc + (size_t)n0 * stride + loff);
            uint w1 = *(const uint*)(xsrc + (size_t)n1 * stride + loff);
            uint w2 = *(const uint*)(xsrc + (size_t)n2 * stride + loff);
            uint w3 = *(const uint*)(xsrc + (size_t)n3 * stride + loff);
            af[0] += bf16_to_f32(w0 & 0xffffu) + bf16_to_f32(w1 & 0xffffu)
                   + bf16_to_f32(w2 & 0xffffu) + bf16_to_f32(w3 & 0xffffu);
            af[1] += bf16_to_f32(w0 >> 16) + bf16_to_f32(w1 >> 16)
                   + bf16_to_f32(w2 >> 16) + bf16_to_f32(w3 >> 16);
        }
    }
    for (; j < e; ++j) {
        int sn = perm[j];
        const ushort* p = xsrc + (size_t)sn * stride + loff;
        if constexpr (W == 256) {
            uint2 w = *(const uint2*)p;
            af[0] += bf16_to_f32(w.x & 0xffffu); af[1] += bf16_to_f32(w.x >> 16);
            af[2] += bf16_to_f32(w.y & 0xffffu); af[3] += bf16_to_f32(w.y >> 16);
        } else {
            uint w = *(const uint*)p;
            af[0] += bf16_to_f32(w & 0xffffu); af[1] += bf16_to_f32(w >> 16);
        }
    }
    ushort* po = out + (size_t)node * W + loff;
    if constexpr (W == 256) {
        uint2 o; o.x = pack_bf16(af[0], af[1]); o.y = pack_bf16(af[2], af[3]);
        *(uint2*)po = o;
    } else {
        *(uint*)po = pack_bf16(af[0], af[1]);
    }
}

// ---------------- conv bf16 MFMA GEMM: 128x128, BK=32, ring-3 depth-2 --------
// (unchanged from R9)

template <int MODE>
__global__ __launch_bounds__(256) void gemm_mfma(
    const ushort* __restrict__ A, const ushort* __restrict__ Bt,
    const float* __restrict__ bias, void* __restrict__ Cout,
    int ldc, int K, float* __restrict__ extra, int Nvalid) {
    __shared__ ushort As[3][128 * 32];
    __shared__ ushort Bs[3][128 * 32];
    const int tid = threadIdx.x;

    const int gx = gridDim.x;
    const int nwg = gx * gridDim.y;
    const int flat = blockIdx.y * gx + blockIdx.x;
    const int q = nwg >> 3, r = nwg & 7;
    const int xcd = flat & 7, loc = flat >> 3;
    const int wg = (xcd < r ? xcd * (q + 1) : r * (q + 1) + (xcd - r) * q) + loc;
    const int bm = (wg / gx) * 128;
    const int bn = (wg % gx) * 128;

    const int lane = tid & 63;
    const int wid = tid >> 6;
    const int wr = wid >> 1, wc = wid & 1;

    f32x4 acc[4][4] = {};

    const int arow = tid >> 2;
    const int gcol = ((tid & 3) ^ ((tid >> 3) & 3)) * 8;
    const ushort* Ag0 = A + (size_t)(bm + arow) * K + gcol;
    const ushort* Ag1 = A + (size_t)(bm + 64 + arow) * K + gcol;
    const ushort* Bg0 = Bt + (size_t)(bn + arow) * K + gcol;
    const ushort* Bg1 = Bt + (size_t)(bn + 64 + arow) * K + gcol;
    const int wofs = (tid & ~63) * 8;

    const int fr = lane & 15;
    const int rchunk = ((lane >> 4) ^ ((fr >> 1) & 3)) * 8;

    const int NT = K >> 5;

    #pragma unroll
    for (int t = 0; t < 2; ++t) {
        const int k0 = t << 5;
        ushort* a = As[t]; ushort* b = Bs[t];
        gload_lds16(Ag0 + k0, a + wofs);
        gload_lds16(Ag1 + k0, a + 2048 + wofs);
        gload_lds16(Bg0 + k0, b + wofs);
        gload_lds16(Bg1 + k0, b + 2048 + wofs);
    }

    int sl = 0;
    for (int it = 0; it < NT; ++it) {
        if (it + 2 < NT) {
            int wsl = sl + 2; if (wsl >= 3) wsl -= 3;
            const int k0 = (it + 2) << 5;
            ushort* a = As[wsl]; ushort* b = Bs[wsl];
            gload_lds16(Ag0 + k0, a + wofs);
            gload_lds16(Ag1 + k0, a + 2048 + wofs);
            gload_lds16(Bg0 + k0, b + wofs);
            gload_lds16(Bg1 + k0, b + 2048 + wofs);
            asm volatile("s_waitcnt vmcnt(8)" ::: "memory");
        } else if (it + 1 < NT) {
            asm volatile("s_waitcnt vmcnt(4)" ::: "memory");
        } else {
            asm volatile("s_waitcnt vmcnt(0)" ::: "memory");
        }
        SCHED_FENCE();
        RAW_BARRIER();

        const ushort* as = As[sl];
        const ushort* bs = Bs[sl];
        short8 af[4], bf[4];
        #pragma unroll
        for (int m = 0; m < 4; ++m)
            af[m] = *(const short8*)&as[(wr * 64 + m * 16 + fr) * 32 + rchunk];
        #pragma unroll
        for (int n = 0; n < 4; ++n)
            bf[n] = *(const short8*)&bs[(wc * 64 + n * 16 + fr) * 32 + rchunk];
        __builtin_amdgcn_s_setprio(1);
        #pragma unroll
        for (int m = 0; m < 4; ++m)
            #pragma unroll
            for (int n = 0; n < 4; ++n)
                acc[m][n] = __builtin_amdgcn_mfma_f32_16x16x32_bf16(af[m], bf[n], acc[m][n], 0, 0, 0);
        __builtin_amdgcn_s_setprio(0);

        asm volatile("s_waitcnt lgkmcnt(0)" ::: "memory");
        SCHED_FENCE();
        RAW_BARRIER();
        sl = sl + 1; if (sl >= 3) sl -= 3;
    }

    float s1[4], s2[4];
    if constexpr (MODE == 0) {
        #pragma unroll
        for (int n = 0; n < 4; ++n) { s1[n] = 0.f; s2[n] = 0.f; }
    }
    #pragma unroll
    for (int n = 0; n < 4; ++n) {
        const int col = bn + wc * 64 + n * 16 + fr;
        const float bv = bias[col];
        #pragma unroll
        for (int m = 0; m < 4; ++m) {
            const int row0 = bm + wr * 64 + m * 16 + (lane >> 4) * 4;
            #pragma unroll
            for (int rr = 0; rr < 4; ++rr) {
                float v = acc[m][n][rr] + bv;
                if constexpr (MODE == 1) {
                    v = fmaxf(v, 0.f);
                    ((ushort*)Cout)[(size_t)(row0 + rr) * ldc + col] = f32_to_bf16(v);
                } else {
                    ((float*)Cout)[(size_t)(row0 + rr) * ldc + col] = v;
                    if (row0 + rr < Nvalid) { s1[n] += v; s2[n] += v * v; }
                }
            }
        }
    }
    if constexpr (MODE == 0) {
        #pragma unroll
        for (int n = 0; n < 4; ++n) {
            float a = s1[n], b = s2[n];
            a += __shfl_xor(a, 16); b += __shfl_xor(b, 16);
            a += __shfl_xor(a, 32); b += __shfl_xor(b, 32);
            if ((lane >> 4) == 0) {
                int col = bn + wc * 64 + n * 16 + fr;
                atomicAdd(&extra[col], a);
                atomicAdd(&extra[256 + col], b);
            }
        }
    }
}

// ---------------- head GEMM: 256x256, BK=64, 8 waves, per-wave 128x64 --------
// m201 geometry: 384 LDS-B/MFMA (8x4 frag reuse). Dbuf LDS (128KB), counted
// vmcnt(8) — tile compute window (~1500cy) covers HBM latency at depth 1.
// LDS rows 64 bf16 = 128 B = 8 chunks; stored chunk = c ^ (row&7); per-16-lane
// quarter -> 2-way residual (free; model matches R10's measured 0 conflicts).

__global__ __launch_bounds__(512) void gemm_head(
    const ushort* __restrict__ A,    // Hcat [MP x 768]
    const ushort* __restrict__ Bt,   // lin1t [768 x 768]
    const float* __restrict__ bias,  // lin1_b [768]
    const float* __restrict__ w2,    // lin2_W [768 x 2]
    float* __restrict__ part,        // [3][MP][2]
    int K, int MP) {
    __shared__ ushort As[2][256 * 64];  // 64 KB
    __shared__ ushort Bs[2][256 * 64];  // 64 KB
    __shared__ float sm_part[256][2];   // 2 KB  -> 130 KB, 1 WG/CU
    const int tid = threadIdx.x;

    // XCD-bijective swizzle (nwg = 3*196 = 588)
    const int gx = gridDim.x;
    const int nwg = gx * gridDim.y;
    const int flat = blockIdx.y * gx + blockIdx.x;
    const int q = nwg >> 3, r = nwg & 7;
    const int xcd = flat & 7, loc = flat >> 3;
    const int wg = (xcd < r ? xcd * (q + 1) : r * (q + 1) + (xcd - r) * q) + loc;
    const int bm = (wg / gx) * 256;
    const int bn = (wg % gx) * 256;
    const int coltile = wg % gx;

    const int lane = tid & 63;
    const int wid = tid >> 6;        // 0..7
    const int wr = wid >> 2;         // 0..1  (128-row band of 256)
    const int wc = wid & 3;          // 0..3  (64-col band of 256)

    sm_part[tid >> 1][tid & 1] = 0.f;

    f32x4 acc[8][4] = {};

    // staging: 8 passes x 64 rows; thread t -> row t>>3 within pass, stored
    // chunk t&7, global chunk = (t&7) ^ ((t>>3)&7)  [inverse of stored swz]
    const int srow = tid >> 3;                       // 0..63
    const int sgc = ((tid & 7) ^ ((tid >> 3) & 7)) * 8;
    const ushort* AgBase = A + (size_t)(bm + srow) * K + sgc;
    const ushort* BgBase = Bt + (size_t)(bn + srow) * K + sgc;
    const size_t rowK64 = (size_t)64 * K;
    const int wofs = (tid & ~63) * 8;                // wave-uniform LDS base

    const int fr = lane & 15;
    const int ch = lane >> 4;                        // 0..3

    const int NT = K >> 6;   // 12

    // prologue: stage tile 0 (8 loads)
    {
        ushort* a = As[0]; ushort* b = Bs[0];
        #pragma unroll
        for (int p = 0; p < 4; ++p) {
            gload_lds16(AgBase + p * rowK64, a + p * 4096 + wofs);
            gload_lds16(BgBase + p * rowK64, b + p * 4096 + wofs);
        }
    }

    for (int it = 0; it < NT; ++it) {
        if (it + 1 < NT) {               // prefetch next tile (8 loads)
            const int kg = (it + 1) << 6;
            ushort* a = As[(it + 1) & 1]; ushort* b = Bs[(it + 1) & 1];
            #pragma unroll
            for (int p = 0; p < 4; ++p) {
                gload_lds16(AgBase + kg + p * rowK64, a + p * 4096 + wofs);
                gload_lds16(BgBase + kg + p * rowK64, b + p * 4096 + wofs);
            }
            asm volatile("s_waitcnt vmcnt(8)" ::: "memory");  // tile it resident
        } else {
            asm volatile("s_waitcnt vmcnt(0)" ::: "memory");
        }
        SCHED_FENCE();
        RAW_BARRIER();

        const ushort* as = As[it & 1];
        const ushort* bs = Bs[it & 1];
        #pragma unroll
        for (int ks = 0; ks < 2; ++ks) {
            const int lc = ks * 4 + ch;              // logical k-chunk
            short8 afr[8], bfr[4];
            #pragma unroll
            for (int m = 0; m < 8; ++m) {
                const int row = wr * 128 + m * 16 + fr;
                afr[m] = *(const short8*)&as[row * 64 + ((lc ^ (row & 7)) * 8)];
            }
            #pragma unroll
            for (int n = 0; n < 4; ++n) {
                const int row = wc * 64 + n * 16 + fr;
                bfr[n] = *(const short8*)&bs[row * 64 + ((lc ^ (row & 7)) * 8)];
            }
            __builtin_amdgcn_s_setprio(1);
            #pragma unroll
            for (int m = 0; m < 8; ++m)
                #pragma unroll
                for (int n = 0; n < 4; ++n)
                    acc[m][n] = __builtin_amdgcn_mfma_f32_16x16x32_bf16(
                        afr[m], bfr[n], acc[m][n], 0, 0, 0);
            __builtin_amdgcn_s_setprio(0);
        }

        asm volatile("s_waitcnt lgkmcnt(0)" ::: "memory");
        SCHED_FENCE();
        RAW_BARRIER();
    }

    // epilogue: relu(v+bias) dot w2 -> reduce over fr -> LDS combine (4 wc waves)
    #pragma unroll
    for (int m = 0; m < 8; ++m) {
        #pragma unroll
        for (int rr = 0; rr < 4; ++rr) {
            float o0 = 0.f, o1 = 0.f;
            #pragma unroll
            for (int n = 0; n < 4; ++n) {
                int col = bn + wc * 64 + n * 16 + fr;
                float v = fmaxf(acc[m][n][rr] + bias[col], 0.f);
                o0 = fmaf(v, w2[col * 2 + 0], o0);
                o1 = fmaf(v, w2[col * 2 + 1], o1);
            }
            o0 += __shfl_xor(o0, 1); o1 += __shfl_xor(o1, 1);
            o0 += __shfl_xor(o0, 2); o1 += __shfl_xor(o1, 2);
            o0 += __shfl_xor(o0, 4); o1 += __shfl_xor(o1, 4);
            o0 += __shfl_xor(o0, 8); o1 += __shfl_xor(o1, 8);
            if (fr == 0) {
                int lrow = wr * 128 + m * 16 + (lane >> 4) * 4 + rr;
                atomicAdd(&sm_part[lrow][0], o0);
                atomicAdd(&sm_part[lrow][1], o1);
            }
        }
    }
    __syncthreads();
    {
        int lrow = tid >> 1, comp = tid & 1;
        part[((size_t)coltile * MP + bm + lrow) * 2 + comp] = sm_part[lrow][comp];
    }
}

// ---------------- BN apply (normalize + relu, write bf16) ----------------

__global__ void bn_apply(const float* __restrict__ h, const float* __restrict__ sums,
                         const float* __restrict__ g, const float* __restrict__ be,
                         ushort* __restrict__ outb, int Nrows) {
    int total = Nrows * 128;
    float inv = 1.0f / (float)Nrows;
    for (int idx = blockIdx.x * blockDim.x + threadIdx.x; idx < total;
         idx += gridDim.x * blockDim.x) {
        int row = idx >> 7;
        int cp = (idx & 127) * 2;
        float2 v = *(const float2*)(h + (size_t)row * 256 + cp);
        float mu0 = sums[cp] * inv,     mu1 = sums[cp + 1] * inv;
        float va0 = sums[256 + cp] * inv - mu0 * mu0;
        float va1 = sums[257 + cp] * inv - mu1 * mu1;
        float o0 = fmaxf((v.x - mu0) * rsqrtf(va0 + 1e-5f) * g[cp]     + be[cp],     0.f);
        float o1 = fmaxf((v.y - mu1) * rsqrtf(va1 + 1e-5f) * g[cp + 1] + be[cp + 1], 0.f);
        *(uint*)(outb + (size_t)row * 256 + cp) = pack_bf16(o0, o1);
    }
}

// ---------------- finalize: sum 3 partials + bias + softmax ----------------

__global__ void finalize3(const float* __restrict__ part, const float* __restrict__ b2,
                          float* __restrict__ out, int Nrows, int MP) {
    int i = blockIdx.x * blockDim.x + threadIdx.x;
    if (i >= Nrows) return;
    float h0 = b2[0], h1 = b2[1];
    #pragma unroll
    for (int c = 0; c < 3; ++c) {
        h0 += part[((size_t)c * MP + i) * 2 + 0];
        h1 += part[((size_t)c * MP + i) * 2 + 1];
    }
    out[2 * i] = h0;
    out[2 * i + 1] = h1;
    float m = fmaxf(h0, h1);
    float e0 = expf(h0 - m), e1 = expf(h1 - m);
    float s = e0 + e1;
    out[(size_t)2 * Nrows + 2 * i] = e0 / s;
    out[(size_t)2 * Nrows + 2 * i + 1] = e1 / s;
}

// ---------------------------------------------------------------------------

extern "C" void kernel_launch(void* const* d_in, const int* in_sizes, int n_in,
                              void* d_out, int out_size, void* d_ws, size_t ws_size,
                              hipStream_t stream) {
    const int N = in_sizes[0] / GIN_N_FEAT_IN;     // 50000
    const int E = in_sizes[1] / 2;                 // 800000
    const int MP = M_PAD_ROWS;
    const int nchunks = (N + 255) / 256;           // 196

    const float* x  = (const float*)d_in[0];
    const int*   ei = (const int*)d_in[1];
    const float* cW1[3] = {(const float*)d_in[2],  (const float*)d_in[8],  (const float*)d_in[14]};
    const float* cb1[3] = {(const float*)d_in[3],  (const float*)d_in[9],  (const float*)d_in[15]};
    const float* cg [3] = {(const float*)d_in[4],  (const float*)d_in[10], (const float*)d_in[16]};
    const float* cbe[3] = {(const float*)d_in[5],  (const float*)d_in[11], (const float*)d_in[17]};
    const float* cW2[3] = {(const float*)d_in[6],  (const float*)d_in[12], (const float*)d_in[18]};
    const float* cb2[3] = {(const float*)d_in[7],  (const float*)d_in[13], (const float*)d_in[19]};
    const float* lin1_W = (const float*)d_in[20];  // [768,768]
    const float* lin1_b = (const float*)d_in[21];
    const float* lin2_W = (const float*)d_in[22];  // [768,2]
    const float* lin2_b = (const float*)d_in[23];
    float* out = (float*)d_out;

    // ---- workspace carve-up (row buffers padded to MP rows) ----
    char* ws = (char*)d_ws;
    size_t off = 0;
    auto carve = [&](size_t bytes) {
        void* p = ws + off;
        off += (bytes + 255) & ~(size_t)255;
        return p;
    };
    ushort* Hcat   = (ushort*)carve((size_t)MP * 768 * 2);   // bf16 h1|h2|h3
    float*  hlin   = (float*) carve((size_t)MP * 256 * 4);   // f32 gemm1 out
    ushort* hlin_b = (ushort*)carve((size_t)MP * 256 * 2);   // bf16 after BN
    ushort* hpre   = (ushort*)carve((size_t)MP * 256 * 2);   // bf16 agg out
    ushort* xb     = (ushort*)carve((size_t)MP * 128 * 2);   // bf16 input
    ushort* w1t[3] = {(ushort*)carve(256 * 256 * 2), (ushort*)carve(256 * 256 * 2),
                      (ushort*)carve(256 * 256 * 2)};
    ushort* w2t[3] = {(ushort*)carve(256 * 256 * 2), (ushort*)carve(256 * 256 * 2),
                      (ushort*)carve(256 * 256 * 2)};
    ushort* lin1t  = (ushort*)carve((size_t)768 * 768 * 2);
    int*   row_st  = (int*)carve((size_t)(N + 1) * 4);
    int*   cursor  = (int*)carve((size_t)N * 4);
    int*   perm    = (int*)carve((size_t)E * 4);
    int*   csums   = (int*)carve(256 * 4);
    float* bnsums  = (float*)carve(512 * 4);
    float* part    = (float*)carve((size_t)3 * MP * 2 * 4);
    (void)ws_size;

    // ---- conversions ----
    cvt_f32_bf16<<<1024, 256, 0, stream>>>(x, xb, N * 64);
    WPrep wp;
    wp.src[0] = cW1[0]; wp.dst[0] = w1t[0]; wp.R[0] = 128; wp.C[0] = 256;
    wp.src[1] = cW1[1]; wp.dst[1] = w1t[1]; wp.R[1] = 256; wp.C[1] = 256;
    wp.src[2] = cW1[2]; wp.dst[2] = w1t[2]; wp.R[2] = 256; wp.C[2] = 256;
    wp.src[3] = cW2[0]; wp.dst[3] = w2t[0]; wp.R[3] = 256; wp.C[3] = 256;
    wp.src[4] = cW2[1]; wp.dst[4] = w2t[1]; wp.R[4] = 256; wp.C[4] = 256;
    wp.src[5] = cW2[2]; wp.dst[5] = w2t[2]; wp.R[5] = 256; wp.C[5] = 256;
    wp.src[6] = lin1_W; wp.dst[6] = lin1t;  wp.R[6] = 768; wp.C[6] = 768;
    prep_weights<<<dim3(576, 7), 256, 0, stream>>>(wp);

    // ---- CSR build (3-stage parallel scan) ----
    hipMemsetAsync(cursor, 0, (size_t)N * 4, stream);
    count_kernel<<<1024, 256, 0, stream>>>(ei, cursor, E);
    scan_chunk<<<nchunks, 256, 0, stream>>>(cursor, row_st, csums, N);
    scan_tops<<<1, 256, 0, stream>>>(csums, row_st, nchunks, N, E);
    scan_add<<<nchunks, 256, 0, stream>>>(row_st, cursor, csums, N);
    scatter_kernel<<<1024, 256, 0, stream>>>(ei, cursor, perm, E);

    const dim3 ggrid(2, MP / 128);       // conv GEMMs (784 WGs, %8==0)
    const int aggblocks = (N + 3) / 4;   // wave per node

    // ---- 3 GIN conv layers ----
    for (int L = 0; L < 3; ++L) {
        if (L == 0)
            agg2<128><<<aggblocks, 256, 0, stream>>>(xb, 128, row_st, perm, hpre, N);
        else
            agg2<256><<<aggblocks, 256, 0, stream>>>(Hcat + (size_t)(L - 1) * 256, 768,
                                                     row_st, perm, hpre, N);

        // GEMM1 + fused BN stats
        hipMemsetAsync(bnsums, 0, 512 * 4, stream);
        gemm_mfma<0><<<ggrid, 256, 0, stream>>>(
            hpre, w1t[L], cb1[L], hlin, 256, (L == 0) ? 128 : 256, bnsums, N);

        bn_apply<<<2048, 256, 0, stream>>>(hlin, bnsums, cg[L], cbe[L], hlin_b, N);

        // GEMM2 -> Hcat column block L (bf16, ldc=768)
        gemm_mfma<1><<<ggrid, 256, 0, stream>>>(
            hlin_b, w2t[L], cb2[L], (void*)(Hcat + (size_t)L * 256), 768, 256,
            nullptr, 0);
    }

    // ---- head: 256x256-tile, BK=64, per-wave 128x64 fused gemm ----
    gemm_head<<<dim3(3, MP / 256), 512, 0, stream>>>(
        Hcat, lin1t, lin1_b, lin2_W, part, 768, MP);

    finalize3<<<(N + 255) / 256, 256, 0, stream>>>(part, lin2_b, out, N, MP);
}